// Round 2
// baseline (717.439 us; speedup 1.0000x reference)
//
#include <hip/hip_runtime.h>

// SymmetricContraction: out[b,c] = sum_w x_w U1[w] w1[b,c]
//                               + sum_{w,v}   x_w x_v   (U2 . w2[b,:,c])_{wv}
//                               + sum_{w,v,i} x_w x_v x_i (U3 . w3[b,:,c])_{wvi}
// x x x fully symmetric -> pre-symmetrized U3 on 816 multisets {a<=b<=c}.
// R2: U tables read via wave-uniform GLOBAL loads (s_load -> SGPR operands,
//     off the LDS pipe which was the R1 bottleneck: 546k cyc/CU ~= dur).
//     Accumulators as float2 -> v_pk_fma_f32 (2 FLOP/lane/instr).

#define B_   1024
#define C_   256
#define L_   16
#define E_   10
#define K3_  23
#define K2_  4

#define NM3  816   // #multisets a<=b<=c of 16
#define NM2  136   // #pairs a<=b
#define K3P  24    // k padded to 24 (96B rows; [23] is zero pad)

typedef float v2f __attribute__((ext_vector_type(2)));

// ---------------- prep: symmetrize U3 / U2 into workspace ----------------
__global__ void prep_kernel(const float* __restrict__ U3,
                            const float* __restrict__ U2,
                            float* __restrict__ wsU3,
                            float* __restrict__ wsU2) {
  int tid = blockIdx.x * blockDim.x + threadIdx.x;
  if (tid < NM3) {
    const int m = tid;
    int aa = 0, bb = 0, cc = 0;
    {
      int t = 0;
      for (int a = 0; a < L_; a++)
        for (int b = a; b < L_; b++)
          for (int c = b; c < L_; c++) {
            if (t == m) { aa = a; bb = b; cc = c; }
            t++;
          }
    }
    int pw[6] = {aa, aa, bb, bb, cc, cc};
    int pv[6] = {bb, cc, aa, cc, aa, bb};
    int pi[6] = {cc, bb, cc, aa, bb, aa};
    bool use[6];
    for (int p = 0; p < 6; p++) {
      bool dup = false;
      for (int q = 0; q < p; q++)
        dup = dup || (pw[p] == pw[q] && pv[p] == pv[q] && pi[p] == pi[q]);
      use[p] = !dup;
    }
    for (int k = 0; k < K3_; k++) {
      float s = 0.f;
      for (int p = 0; p < 6; p++)
        if (use[p]) s += U3[((pw[p] * L_ + pv[p]) * L_ + pi[p]) * K3_ + k];
      wsU3[m * K3P + k] = s;
    }
    wsU3[m * K3P + K3_] = 0.f;  // pad
  } else if (tid < NM3 + NM2) {
    const int pidx = tid - NM3;
    int aa = 0, bb = 0;
    int t = 0;
    for (int a = 0; a < L_; a++)
      for (int b = a; b < L_; b++) {
        if (t == pidx) { aa = a; bb = b; }
        t++;
      }
    for (int k2 = 0; k2 < K2_; k2++) {
      float s = U2[(aa * L_ + bb) * K2_ + k2];
      if (aa != bb) s += U2[(bb * L_ + aa) * K2_ + k2];
      wsU2[pidx * K2_ + k2] = s;
    }
  }
}

// ---------------- main: one thread per (b,c) ----------------
// block = 512 threads = 2 b's x 256 c's; grid = 512 blocks.
__global__ __launch_bounds__(512) void symcon_kernel(
    const float* __restrict__ x,    // [B,C,L]
    const float* __restrict__ y,    // [B,E]
    const float* __restrict__ U1,   // [L,1]
    const float* __restrict__ W3,   // [E,K3,C]
    const float* __restrict__ W2,   // [E,K2,C]
    const float* __restrict__ W1,   // [E,1,C]
    const float* __restrict__ wsU3, // [NM3,K3P]  grid-uniform table
    const float* __restrict__ wsU2, // [NM2,K2]
    float* __restrict__ out)        // [B,C]
{
  __shared__ float sX[512 * 17];  // 34816 B; stride 17 -> only 2-way bank aliasing (free)

  const int tid = threadIdx.x;
  const int c   = tid & (C_ - 1);
  const int row = blockIdx.x * 512 + tid;  // == b*C_ + c
  const int b   = row >> 8;                // wave-uniform

  // stage this thread's x row into LDS (coalesced float4 global reads)
  float* xrow = &sX[tid * 17];
  {
    const float4* xg = (const float4*)(x + (size_t)row * L_);
    #pragma unroll
    for (int i = 0; i < 4; i++) {
      float4 v = xg[i];
      xrow[i * 4 + 0] = v.x; xrow[i * 4 + 1] = v.y;
      xrow[i * 4 + 2] = v.z; xrow[i * 4 + 3] = v.w;
    }
  }
  __syncthreads();

  // ---- nu=3 core: t[k] = sum_m x_a x_b x_c * Us3[m,k] ----
  // U row address is uniform (loop-counter-derived) -> s_load; 12 v_pk_fma_f32.
  v2f t[K3P / 2];
  #pragma unroll
  for (int i = 0; i < K3P / 2; i++) t[i] = (v2f){0.f, 0.f};

  const float* __restrict__ up = wsU3;
  for (int a = 0; a < L_; a++) {
    const float xa = xrow[a];
    for (int bb = a; bb < L_; bb++) {
      const float xab = xa * xrow[bb];
      for (int cc = bb; cc < L_; cc++) {
        const float xabc = xab * xrow[cc];   // 1 ds_read_b32 + 1 v_mul
        const v2f xv = (v2f){xabc, xabc};
        const v2f* __restrict__ u2 = (const v2f*)up;
        #pragma unroll
        for (int i = 0; i < K3P / 2; i++)
          t[i] += u2[i] * xv;                // v_pk_fma_f32, SGPR src
        up += K3P;
      }
    }
  }

  // ---- epilogue ----
  float yreg[E_];
  #pragma unroll
  for (int e = 0; e < E_; e++) yreg[e] = y[b * E_ + e];  // wave-uniform -> s_load

  float result = 0.f;
  // nu=3: contract t with w3[b,:,c]  (W3 reads coalesced over c, L2-resident)
  #pragma unroll
  for (int k = 0; k < K3_; k++) {
    float w3k = 0.f;
    #pragma unroll
    for (int e = 0; e < E_; e++) w3k += W3[(e * K3_ + k) * C_ + c] * yreg[e];
    const float tk = (k & 1) ? t[k >> 1].y : t[k >> 1].x;
    result += tk * w3k;
  }

  // nu=2
  float w2r[K2_];
  #pragma unroll
  for (int k2 = 0; k2 < K2_; k2++) {
    float s = 0.f;
    #pragma unroll
    for (int e = 0; e < E_; e++) s += W2[(e * K2_ + k2) * C_ + c] * yreg[e];
    w2r[k2] = s;
  }
  {
    float acc2 = 0.f;
    const float* __restrict__ u2p = wsU2;   // uniform -> s_load
    for (int a = 0; a < L_; a++) {
      const float xa = xrow[a];
      for (int b2 = a; b2 < L_; b2++) {
        const float pab = xa * xrow[b2];
        acc2 += pab * (u2p[0] * w2r[0] + u2p[1] * w2r[1] +
                       u2p[2] * w2r[2] + u2p[3] * w2r[3]);
        u2p += K2_;
      }
    }
    result += acc2;
  }

  // nu=1
  {
    float w1v = 0.f;
    #pragma unroll
    for (int e = 0; e < E_; e++) w1v += W1[e * C_ + c] * yreg[e];
    float u1x = 0.f;
    #pragma unroll
    for (int w = 0; w < L_; w++) u1x += U1[w] * xrow[w];
    result += w1v * u1x;
  }

  out[row] = result;
}

extern "C" void kernel_launch(void* const* d_in, const int* in_sizes, int n_in,
                              void* d_out, int out_size, void* d_ws, size_t ws_size,
                              hipStream_t stream) {
  const float* x  = (const float*)d_in[0];
  const float* y  = (const float*)d_in[1];
  const float* U3 = (const float*)d_in[2];
  const float* U2 = (const float*)d_in[3];
  const float* U1 = (const float*)d_in[4];
  const float* W3 = (const float*)d_in[5];
  const float* W2 = (const float*)d_in[6];
  const float* W1 = (const float*)d_in[7];
  float* out = (float*)d_out;

  float* wsU3 = (float*)d_ws;            // 816*24 floats = 78336 B
  float* wsU2 = wsU3 + NM3 * K3P;        // 136*4 floats  =  2176 B

  prep_kernel<<<dim3(4), dim3(256), 0, stream>>>(U3, U2, wsU3, wsU2);
  symcon_kernel<<<dim3(B_ * C_ / 512), dim3(512), 0, stream>>>(
      x, y, U1, W3, W2, W1, wsU3, wsU2, out);
}

// Round 3
// 491.879 us; speedup vs baseline: 1.4586x; 1.4586x over previous
//
#include <hip/hip_runtime.h>

// SymmetricContraction on MI355X.
// Model (verified R1/R2): LDS pipe issues ~5.8 cyc/instr per CU -> cost =
// waves/CU x LDS-instrs/iter. R3 cuts both: 4 rows/thread (one ds_read_b128
// serves 4 rows) and U3s packed as f16 (m,m+1)-pairs consumed by
// v_dot2_f32_f16 (3 b128 per multiset instead of 6).
// R2 lesson: uniform global loads do NOT scalarize to s_load; keep U in LDS.

#define B_   1024
#define C_   256
#define L_   16
#define E_   10
#define K3_  23
#define K2_  4
#define K3P  24      // k padded to 24 dwords per pair (96B rows)
#define NPAIR3 444   // dot2 pairs: sum over (a<=b) of ceil((16-b)/2)
#define NM2  136

typedef _Float16 half2_t __attribute__((ext_vector_type(2)));

// ---------------- prep: symmetrize U3 -> f16 pairs, U2 -> fp32 ----------------
__device__ inline float sym_u3(const float* __restrict__ U3, int a, int b, int c, int k) {
  int pw[6] = {a, a, b, b, c, c};
  int pv[6] = {b, c, a, c, a, b};
  int pi[6] = {c, b, c, a, b, a};
  float s = 0.f;
  for (int p = 0; p < 6; p++) {
    bool dup = false;
    for (int q = 0; q < p; q++)
      dup = dup || (pw[p] == pw[q] && pv[p] == pv[q] && pi[p] == pi[q]);
    if (!dup) s += U3[((pw[p] * L_ + pv[p]) * L_ + pi[p]) * K3_ + k];
  }
  return s;
}

__global__ void prep_kernel(const float* __restrict__ U3,
                            const float* __restrict__ U2,
                            unsigned int* __restrict__ wsU3h,  // [NPAIR3][K3P] half2
                            float* __restrict__ wsU2) {        // [NM2][K2]
  const int tid = threadIdx.x;  // one thread per (a,b); grid = 1 block x 256
  if (tid >= NM2) return;
  // decode tid -> (a,b) in the same (a<=b) enumeration order as the main loop
  int a = 0, b = 0, t = 0, pbase = 0;
  bool found = false;
  for (int aa = 0; aa < L_ && !found; aa++) {
    for (int bb = aa; bb < L_; bb++) {
      if (t == tid) { a = aa; b = bb; found = true; break; }
      pbase += (17 - bb) >> 1;
      t++;
    }
  }
  // U2 symmetrized (order matches main kernel's (a<=b) loop)
  for (int k2 = 0; k2 < K2_; k2++) {
    float s = U2[(a * L_ + b) * K2_ + k2];
    if (a != b) s += U2[(b * L_ + a) * K2_ + k2];
    wsU2[tid * K2_ + k2] = s;
  }
  // U3 dot2 pairs for this (a,b) run: c0 = b+2p, c1 = c0+1 (zero-pad past 15)
  const int np = (17 - b) >> 1;
  for (int p = 0; p < np; p++) {
    const int c0 = b + 2 * p, c1 = c0 + 1;
    for (int k = 0; k < K3P; k++) {
      float s0 = (k < K3_) ? sym_u3(U3, a, b, c0, k) : 0.f;
      float s1 = (k < K3_ && c1 < L_) ? sym_u3(U3, a, b, c1, k) : 0.f;
      half2_t h;
      h.x = (_Float16)s0;
      h.y = (_Float16)s1;
      wsU3h[(pbase + p) * K3P + k] = __builtin_bit_cast(unsigned int, h);
    }
  }
}

// ---------------- main: one thread = 4 rows (4 b's, same c) ----------------
// grid 256 blocks x 256 threads; block bq handles b in [4bq,4bq+4), c = tid.
__global__ __launch_bounds__(256, 1) void symcon_kernel(
    const float* __restrict__ x,    // [B,C,L]
    const float* __restrict__ y,    // [B,E]
    const float* __restrict__ U1,   // [L,1]
    const float* __restrict__ W3,   // [E,K3,C]
    const float* __restrict__ W2,   // [E,K2,C]
    const float* __restrict__ W1,   // [E,1,C]
    const unsigned int* __restrict__ wsU3h,
    const float* __restrict__ wsU2,
    float* __restrict__ out)        // [B,C]
{
  // x: per-thread 16 slots x 4 rows, stride 68 floats (17 float4s: odd ->
  // lanes spread over all 8 bank-quads, conflict-free; 16B aligned).
  __shared__ __align__(16) float sX[256 * 68];             // 69632 B
  __shared__ __align__(16) unsigned int sU3[NPAIR3 * K3P]; // 42624 B
  __shared__ __align__(16) float sU2[NM2 * K2_];           //  2176 B

  const int tid = threadIdx.x;   // == c
  const int bq  = blockIdx.x;

  // stage U tables
  for (int i = tid; i < NPAIR3 * K3P / 4; i += 256)
    ((uint4*)sU3)[i] = ((const uint4*)wsU3h)[i];
  for (int i = tid; i < NM2 * K2_ / 4; i += 256)
    ((float4*)sU2)[i] = ((const float4*)wsU2)[i];

  // stage x: 4 rows interleaved [slot][row]
  {
    float* xdst = &sX[tid * 68];
    for (int r = 0; r < 4; r++) {
      const float4* xg = (const float4*)(x + ((size_t)(bq * 4 + r) * C_ + tid) * L_);
      #pragma unroll
      for (int i = 0; i < 4; i++) {
        float4 v = xg[i];
        xdst[(i * 4 + 0) * 4 + r] = v.x;
        xdst[(i * 4 + 1) * 4 + r] = v.y;
        xdst[(i * 4 + 2) * 4 + r] = v.z;
        xdst[(i * 4 + 3) * 4 + r] = v.w;
      }
    }
  }
  __syncthreads();

  const float* xs = &sX[tid * 68];
#define XS(cc) (*(const float4*)&xs[(cc) * 4])

  // ---- nu=3 core: t[r][k] = sum_m xa xb xc * U3s[m][k], dot2 over m-pairs ----
  float tacc[4][K3_];
  #pragma unroll
  for (int r = 0; r < 4; r++)
    #pragma unroll
    for (int k = 0; k < K3_; k++) tacc[r][k] = 0.f;

  const uint4* up = (const uint4*)sU3;
  #pragma unroll 1
  for (int a = 0; a < L_; a++) {
    const float4 xa = XS(a);
    #pragma unroll 1
    for (int b = a; b < L_; b++) {
      const float4 xbv = XS(b);
      float4 xab;
      xab.x = xa.x * xbv.x; xab.y = xa.y * xbv.y;
      xab.z = xa.z * xbv.z; xab.w = xa.w * xbv.w;
      const int np = (17 - b) >> 1;
      #pragma unroll 2
      for (int p = 0; p < np; p++) {
        const int c0 = b + 2 * p;
        const int c1 = (c0 + 1 < L_) ? c0 + 1 : L_ - 1;  // pad reads slot 15 (U=0)
        const float4 xc0 = XS(c0);
        const float4 xc1 = XS(c1);
        half2_t h[4];
        h[0].x = (_Float16)(xab.x * xc0.x); h[0].y = (_Float16)(xab.x * xc1.x);
        h[1].x = (_Float16)(xab.y * xc0.y); h[1].y = (_Float16)(xab.y * xc1.y);
        h[2].x = (_Float16)(xab.z * xc0.z); h[2].y = (_Float16)(xab.z * xc1.z);
        h[3].x = (_Float16)(xab.w * xc0.w); h[3].y = (_Float16)(xab.w * xc1.w);
        uint4 q0 = up[0], q1 = up[1], q2 = up[2], q3 = up[3], q4 = up[4], q5 = up[5];
        up += 6;
        const unsigned int uu[K3P] = {q0.x, q0.y, q0.z, q0.w, q1.x, q1.y, q1.z, q1.w,
                                      q2.x, q2.y, q2.z, q2.w, q3.x, q3.y, q3.z, q3.w,
                                      q4.x, q4.y, q4.z, q4.w, q5.x, q5.y, q5.z, q5.w};
        #pragma unroll
        for (int k = 0; k < K3_; k++) {
          const half2_t uh = __builtin_bit_cast(half2_t, uu[k]);
          #pragma unroll
          for (int r = 0; r < 4; r++)
            tacc[r][k] = __builtin_amdgcn_fdot2(h[r], uh, tacc[r][k], false);
        }
      }
    }
  }

  // ---- epilogue ----
  float yr[4][E_];
  #pragma unroll
  for (int r = 0; r < 4; r++)
    #pragma unroll
    for (int e = 0; e < E_; e++) yr[r][e] = y[(size_t)(bq * 4 + r) * E_ + e];

  float res0 = 0.f, res1 = 0.f, res2 = 0.f, res3 = 0.f;
  // nu=3 contraction with w3 (W3 reads coalesced over c = tid)
  #pragma unroll 1
  for (int k = 0; k < K3_; k++) {
    float wk0 = 0.f, wk1 = 0.f, wk2 = 0.f, wk3 = 0.f;
    #pragma unroll
    for (int e = 0; e < E_; e++) {
      const float w = W3[((size_t)e * K3_ + k) * C_ + tid];
      wk0 += w * yr[0][e]; wk1 += w * yr[1][e];
      wk2 += w * yr[2][e]; wk3 += w * yr[3][e];
    }
    res0 += tacc[0][k] * wk0; res1 += tacc[1][k] * wk1;
    res2 += tacc[2][k] * wk2; res3 += tacc[3][k] * wk3;
  }

  // nu=2 / nu=1 weights
  float w2v[4][K2_];
  #pragma unroll
  for (int k2 = 0; k2 < K2_; k2++) {
    #pragma unroll
    for (int r = 0; r < 4; r++) w2v[r][k2] = 0.f;
    #pragma unroll
    for (int e = 0; e < E_; e++) {
      const float w = W2[((size_t)e * K2_ + k2) * C_ + tid];
      w2v[0][k2] += w * yr[0][e]; w2v[1][k2] += w * yr[1][e];
      w2v[2][k2] += w * yr[2][e]; w2v[3][k2] += w * yr[3][e];
    }
  }
  float w1v[4] = {0.f, 0.f, 0.f, 0.f};
  #pragma unroll
  for (int e = 0; e < E_; e++) {
    const float w = W1[(size_t)e * C_ + tid];
    w1v[0] += w * yr[0][e]; w1v[1] += w * yr[1][e];
    w1v[2] += w * yr[2][e]; w1v[3] += w * yr[3][e];
  }

  float4 acc2 = {0.f, 0.f, 0.f, 0.f};
  float4 u1x  = {0.f, 0.f, 0.f, 0.f};
  const float4* u2p = (const float4*)sU2;
  #pragma unroll 1
  for (int a = 0; a < L_; a++) {
    const float4 xa = XS(a);
    const float ua = U1[a];
    u1x.x += ua * xa.x; u1x.y += ua * xa.y;
    u1x.z += ua * xa.z; u1x.w += ua * xa.w;
    #pragma unroll 1
    for (int b = a; b < L_; b++) {
      const float4 xbv = XS(b);
      const float4 u2 = *u2p++;
      const float s0 = u2.x * w2v[0][0] + u2.y * w2v[0][1] + u2.z * w2v[0][2] + u2.w * w2v[0][3];
      const float s1 = u2.x * w2v[1][0] + u2.y * w2v[1][1] + u2.z * w2v[1][2] + u2.w * w2v[1][3];
      const float s2 = u2.x * w2v[2][0] + u2.y * w2v[2][1] + u2.z * w2v[2][2] + u2.w * w2v[2][3];
      const float s3 = u2.x * w2v[3][0] + u2.y * w2v[3][1] + u2.z * w2v[3][2] + u2.w * w2v[3][3];
      acc2.x += xa.x * xbv.x * s0; acc2.y += xa.y * xbv.y * s1;
      acc2.z += xa.z * xbv.z * s2; acc2.w += xa.w * xbv.w * s3;
    }
  }
  res0 += acc2.x + w1v[0] * u1x.x;
  res1 += acc2.y + w1v[1] * u1x.y;
  res2 += acc2.z + w1v[2] * u1x.z;
  res3 += acc2.w + w1v[3] * u1x.w;

  out[(size_t)(bq * 4 + 0) * C_ + tid] = res0;
  out[(size_t)(bq * 4 + 1) * C_ + tid] = res1;
  out[(size_t)(bq * 4 + 2) * C_ + tid] = res2;
  out[(size_t)(bq * 4 + 3) * C_ + tid] = res3;
#undef XS
}

extern "C" void kernel_launch(void* const* d_in, const int* in_sizes, int n_in,
                              void* d_out, int out_size, void* d_ws, size_t ws_size,
                              hipStream_t stream) {
  const float* x  = (const float*)d_in[0];
  const float* y  = (const float*)d_in[1];
  const float* U3 = (const float*)d_in[2];
  const float* U2 = (const float*)d_in[3];
  const float* U1 = (const float*)d_in[4];
  const float* W3 = (const float*)d_in[5];
  const float* W2 = (const float*)d_in[6];
  const float* W1 = (const float*)d_in[7];
  float* out = (float*)d_out;

  unsigned int* wsU3h = (unsigned int*)d_ws;      // 444*24*4 = 42624 B
  float* wsU2 = (float*)(wsU3h + NPAIR3 * K3P);   // 136*4*4  =  2176 B

  prep_kernel<<<dim3(1), dim3(256), 0, stream>>>(U3, U2, wsU3h, wsU2);
  symcon_kernel<<<dim3(C_), dim3(256), 0, stream>>>(
      x, y, U1, W3, W2, W1, wsU3h, wsU2, out);
}